// Round 1
// baseline (1285.077 us; speedup 1.0000x reference)
//
#include <hip/hip_runtime.h>
#include <math.h>

#define B_   2
#define N_   4096
#define S_   48
#define NPL  32
#define NRAYS (B_*N_)          // 8192
#define NPTS  (NRAYS*S_)       // 393216
#define DELTA_ (2.0f/47.0f)

// ---- workspace layout (float offsets) ----
#define OFF_POSES  0                    // 32*12 = 384
#define OFF_MINMAX 384                  // 2 uints (gmin/gmax bit patterns)
#define OFF_W2T    512                  // 33*64 = 2112 (W2 transposed)
#define OFF_DC     4096                 // depths_c  [NPTS]
#define OFF_DF     (OFF_DC+NPTS)        // depths_f  [NPTS]
#define OFF_SC     (OFF_DF+NPTS)        // dens_c    [NPTS]
#define OFF_SF     (OFF_SC+NPTS)        // dens_f    [NPTS]
#define OFF_CC     (OFF_SF+NPTS)        // colors_c  [NPTS*32]
#define OFF_CF     (OFF_CC+NPTS*32)     // colors_f  [NPTS*32]
// total = OFF_CF + NPTS*32 = 26,742,784 floats = ~107 MB

__device__ __forceinline__ float softplus_f(float x) {
    return fmaxf(x, 0.f) + log1pf(expf(-fabsf(x)));
}

__device__ void mul3(const double* a, const double* b, double* o) {
    for (int i = 0; i < 3; i++)
        for (int j = 0; j < 3; j++) {
            double s = 0.0;
            for (int k = 0; k < 3; k++) s += a[i*3+k]*b[k*3+j];
            o[i*3+j] = s;
        }
}

// ---- kernel 0: poses (double math, faithful to numpy), min/max init, W2 transpose ----
__global__ void k_init(float* ws, const float* __restrict__ W2) {
    int t = threadIdx.x;
    if (t < 32) {
        double y = 1.0 - (t/31.0)*2.0;
        double rr = sqrt(fmax(1.0 - y*y, 0.0));
        double golden = M_PI*(sqrt(5.0) - 1.0);
        double th = golden*(double)t;
        double x = cos(th)*rr, z = sin(th)*rr;
        double phi   = atan2(z, sqrt(x*x + y*y));   // radians, treated as degrees below
        double theta = atan2(y, x);
        double p  = phi/180.0*M_PI;
        double tt = theta/180.0*M_PI;
        double e  = 90.0/180.0*M_PI;
        double cp = cos(p), sp = sin(p), ct = cos(tt), st = sin(tt);
        double ce = cos(e), se = sin(e);
        double Ph[9] = {1,0,0,  0,cp,-sp,  0,sp,cp};
        double Th[9] = {ct,0,-st,  0,1,0,  st,0,ct};
        double Et[9] = {ce,se,0,  -se,ce,0,  0,0,1};
        double M3[9] = {-1,0,0,  0,0,1,  0,1,0};
        double A[9], Bm[9], R[9];
        mul3(Th, Ph, A);   // rot_theta @ rot_phi
        mul3(Et, A, Bm);   // rot_eta @ ...
        mul3(M3, Bm, R);   // M @ c2w rotation
        double radius = -1.307;
        double tv0 = radius*R[2], tv1 = radius*R[5], tv2 = radius*R[8]; // R @ (0,0,r)
        // flip: negate column 0
        double Rf[9] = {-R[0],R[1],R[2], -R[3],R[4],R[5], -R[6],R[7],R[8]};
        // inv([Rf|tv]) rows = [Rf^T | -Rf^T tv]
        float* P = ws + OFF_POSES + t*12;
        for (int j = 0; j < 3; j++) {
            double r0 = Rf[0*3+j], r1 = Rf[1*3+j], r2 = Rf[2*3+j];
            P[j*4+0] = (float)r0;
            P[j*4+1] = (float)r1;
            P[j*4+2] = (float)r2;
            P[j*4+3] = (float)(-(r0*tv0 + r1*tv1 + r2*tv2));
        }
    }
    if (t == 32) ((unsigned*)(ws + OFF_MINMAX))[0] = 0x7F800000u; // +inf (min slot)
    if (t == 33) ((unsigned*)(ws + OFF_MINMAX))[1] = 0u;          // 0    (max slot, depths>0)
    for (int idx = t; idx < 33*64; idx += 64) {
        int jo = idx >> 6, i = idx & 63;
        ws[OFF_W2T + idx] = W2[i*33 + jo];
    }
}

// ---- kernel 1: coarse depths + global min/max ----
__global__ void k_depths(const float* __restrict__ noise, float* ws) {
    int g = blockIdx.x*256 + threadIdx.x;
    if (g >= NPTS) return;
    int j = g % S_;
    float v = 0.5f + (float)j*DELTA_ + noise[g]*DELTA_;
    ws[OFF_DC + g] = v;
    float mn = v, mx = v;
    for (int off = 32; off > 0; off >>= 1) {
        mn = fminf(mn, __shfl_down(mn, off));
        mx = fmaxf(mx, __shfl_down(mx, off));
    }
    if ((threadIdx.x & 63) == 0) {
        atomicMin(((unsigned*)(ws + OFF_MINMAX)) + 0, __float_as_uint(mn));
        atomicMax(((unsigned*)(ws + OFF_MINMAX)) + 1, __float_as_uint(mx));
    }
}

// ---- kernel 2/4: fused point pass (project + sample 32 planes + MLP) ----
__global__ __launch_bounds__(256) void k_pass(
    const float* __restrict__ planes, const float* __restrict__ ro,
    const float* __restrict__ rd, const float* __restrict__ depths,
    const float* __restrict__ W1, const float* __restrict__ b1,
    const float* __restrict__ W2t, const float* __restrict__ b2,
    const float* __restrict__ poses,
    float* __restrict__ colors, float* __restrict__ dens)
{
    int g = blockIdx.x*256 + threadIdx.x;
    if (g >= NPTS) return;
    int ray = g / S_;
    int b = ray >> 12;   // /4096
    float depth = depths[g];
    float ox = ro[ray*3+0], oy = ro[ray*3+1], oz = ro[ray*3+2];
    float dx = rd[ray*3+0], dy = rd[ray*3+1], dz = rd[ray*3+2];
    float px = ox + depth*dx, py = oy + depth*dy, pz = oz + depth*dz;

    float h[64];
#pragma unroll
    for (int j = 0; j < 64; j++) h[j] = b1[j];

    const float* pb = planes + (size_t)b*96*64*64;
    for (int k = 0; k < NPL; k++) {
        const float* P = poses + k*12;
        float c0 = P[0]*px + P[1]*py + P[2]*pz  + P[3];
        float c1 = P[4]*px + P[5]*py + P[6]*pz  + P[7];
        float c2 = P[8]*px + P[9]*py + P[10]*pz + P[11];
        float rz = __builtin_amdgcn_rcpf(c2);
        float gx = (1.0254f*c0 + 0.5f*c2)*rz;
        float gy = (1.0254f*c1 + 0.5f*c2)*rz;
        gx = fminf(fmaxf(gx, 0.f), 1.f)*2.f - 1.f;
        gy = fminf(fmaxf(gy, 0.f), 1.f)*2.f - 1.f;
        float ix = ((gx + 1.f)*64.f - 1.f)*0.5f;
        float iy = ((gy + 1.f)*64.f - 1.f)*0.5f;
        float x0f = floorf(ix), y0f = floorf(iy);
        float wx = ix - x0f, wy = iy - y0f;
        int x0 = (int)x0f, y0 = (int)y0f;
        float f0 = 0.f, f1 = 0.f, f2 = 0.f;
        const float* cb0 = pb + (size_t)(k*3)*4096;
#pragma unroll
        for (int dyi = 0; dyi < 2; dyi++) {
            int yy = y0 + dyi;
            if (yy < 0 || yy > 63) continue;
            float wyv = dyi ? wy : 1.f - wy;
#pragma unroll
            for (int dxi = 0; dxi < 2; dxi++) {
                int xx = x0 + dxi;
                if (xx < 0 || xx > 63) continue;
                float w = wyv*(dxi ? wx : 1.f - wx);
                const float* q = cb0 + yy*64 + xx;
                f0 = fmaf(w, q[0],    f0);
                f1 = fmaf(w, q[4096], f1);
                f2 = fmaf(w, q[8192], f2);
            }
        }
        const float* w1f = W1 + (k*3)*64;        // 3 contiguous feat rows
        const float* w1p = W1 + (96 + 2*k)*64;   // 2 contiguous pix rows
#pragma unroll
        for (int j = 0; j < 64; j++) {
            float acc = h[j];
            acc = fmaf(f0, w1f[j],      acc);
            acc = fmaf(f1, w1f[64+j],   acc);
            acc = fmaf(f2, w1f[128+j],  acc);
            acc = fmaf(gx, w1p[j],      acc);
            acc = fmaf(gy, w1p[64+j],   acc);
            h[j] = acc;
        }
    }
#pragma unroll
    for (int j = 0; j < 64; j++) h[j] = softplus_f(h[j]);

    { // sigma (raw)
        float o0 = b2[0];
#pragma unroll
        for (int i = 0; i < 64; i++) o0 = fmaf(h[i], W2t[i], o0);
        dens[g] = o0;
    }
    float* cw = colors + (size_t)g*32;
    for (int jo = 1; jo < 33; jo++) {
        float acc = b2[jo];
        const float* wr = W2t + jo*64;
#pragma unroll
        for (int i = 0; i < 64; i++) acc = fmaf(h[i], wr[i], acc);
        float sg = 1.f/(1.f + expf(-acc));
        cw[jo-1] = fmaf(sg, 1.002f, -0.001f);
    }
}

// ---- kernel 3: coarse ray march -> smoothed pdf -> importance samples ----
__global__ __launch_bounds__(128) void k_imp(const float* __restrict__ u, float* ws) {
    __shared__ float wls[128][47];
    __shared__ float cdfl[128][46];
    int tid = threadIdx.x;
    int r = blockIdx.x*128 + tid;
    if (r >= NRAYS) return;
    const float* z   = ws + OFF_DC + (size_t)r*S_;
    const float* den = ws + OFF_SC + (size_t)r*S_;
    float T = 1.f;
    float pd = z[0], ps = den[0];
    for (int i = 0; i < 47; i++) {
        float dd = z[i+1], ss = den[i+1];
        float delta = dd - pd;
        float sp = softplus_f(0.5f*(ps + ss) - 1.f);
        float alpha = 1.f - expf(-sp*delta);
        wls[tid][i] = alpha*T;
        T *= (1.f - alpha + 1e-10f);
        pd = dd; ps = ss;
    }
    // maxpool(k2,s1,p1) then avgpool(k2,s1), keep sm[1:-1]: pw[t]=sm[t+1], t=0..44
    float csum = 0.f;
    for (int t = 0; t < 45; t++) {
        float m1 = fmaxf(wls[tid][t],   wls[tid][t+1]);   // m[t+1]
        float m2 = fmaxf(wls[tid][t+1], wls[tid][t+2]);   // m[t+2]
        float pw = 0.5f*(m1 + m2) + 0.01f + 1e-5f;        // + sample_pdf eps
        csum += pw;
        wls[tid][t] = pw;   // safe: future t' reads wls[t'..t'+2], all > t
    }
    cdfl[tid][0] = 0.f;
    float run = 0.f;
    for (int t = 0; t < 45; t++) { run += wls[tid][t]/csum; cdfl[tid][t+1] = run; }

    float* dF = ws + OFF_DF + (size_t)r*S_;
    for (int t = 0; t < 48; t++) {
        float uu = u[(size_t)r*48 + t];
        int lo = 0, hi = 46;                      // searchsorted(cdf, u, 'right')
        while (lo < hi) {
            int mid = (lo + hi) >> 1;
            if (uu >= cdfl[tid][mid]) lo = mid + 1; else hi = mid;
        }
        int below = lo - 1; if (below < 0) below = 0;
        int above = lo < 45 ? lo : 45;
        float cb = cdfl[tid][below], ca = cdfl[tid][above];
        float zb = z[below], za = z[above];
        float dn = ca - cb; if (dn < 1e-5f) dn = 1.f;
        dF[t] = zb + (uu - cb)/dn*(za - zb);
    }
}

// ---- kernel 5: merge+stable-sort 96 samples, final march, output [B,N,34] ----
__global__ __launch_bounds__(64) void k_final(float* __restrict__ out, const float* __restrict__ ws) {
    __shared__ float dl[64][97];   // pad 97: avoid 32-bank aliasing
    __shared__ short il[64][96];
    int tid = threadIdx.x;
    int r = blockIdx.x*64 + tid;
    if (r >= NRAYS) return;
    const float* dc = ws + OFF_DC + (size_t)r*48;
    const float* df = ws + OFF_DF + (size_t)r*48;
    for (int i = 0; i < 48; i++) { dl[tid][i]    = dc[i]; il[tid][i]    = (short)i; }
    for (int i = 0; i < 48; i++) { dl[tid][48+i] = df[i]; il[tid][48+i] = (short)(48+i); }
    // first 48 already ascending; stable insertion of fine samples (strict > keeps
    // original-index order on ties, matching stable argsort)
    for (int j = 48; j < 96; j++) {
        float key = dl[tid][j]; short kid = il[tid][j];
        int i = j - 1;
        while (i >= 0 && dl[tid][i] > key) {
            dl[tid][i+1] = dl[tid][i]; il[tid][i+1] = il[tid][i]; i--;
        }
        dl[tid][i+1] = key; il[tid][i+1] = kid;
    }
    const float* cC = ws + OFF_CC; const float* cF = ws + OFF_CF;
    const float* sC = ws + OFF_SC; const float* sF = ws + OFF_SF;

    int s0 = il[tid][0];
    size_t idx0 = (size_t)r*48 + (s0 < 48 ? s0 : s0 - 48);
    float d_prev  = dl[tid][0];
    float den_prev = (s0 < 48) ? sC[idx0] : sF[idx0];
    const float4* cp = (const float4*)(((s0 < 48) ? cC : cF) + idx0*32);
    float4 cur[8], rgb[8];
#pragma unroll
    for (int q = 0; q < 8; q++) { cur[q] = cp[q]; rgb[q] = make_float4(0.f,0.f,0.f,0.f); }

    float T = 1.f, wsum = 0.f, dsum = 0.f;
    for (int i = 1; i < 96; i++) {
        int si = il[tid][i];
        float di = dl[tid][i];
        size_t idx = (size_t)r*48 + (si < 48 ? si : si - 48);
        float deni = (si < 48) ? sC[idx] : sF[idx];
        const float4* np_ = (const float4*)(((si < 48) ? cC : cF) + idx*32);
        float delta = di - d_prev;
        float sp = softplus_f(0.5f*(den_prev + deni) - 1.f);
        float alpha = 1.f - expf(-sp*delta);
        float wgt = alpha*T;
        T *= (1.f - alpha + 1e-10f);
        wsum += wgt;
        dsum += wgt*0.5f*(d_prev + di);
#pragma unroll
        for (int q = 0; q < 8; q++) {
            float4 nx = np_[q];
            rgb[q].x += wgt*0.5f*(cur[q].x + nx.x);
            rgb[q].y += wgt*0.5f*(cur[q].y + nx.y);
            rgb[q].z += wgt*0.5f*(cur[q].z + nx.z);
            rgb[q].w += wgt*0.5f*(cur[q].w + nx.w);
            cur[q] = nx;
        }
        d_prev = di; den_prev = deni;
    }
    float gmn = __uint_as_float(((const unsigned*)(ws + OFF_MINMAX))[0]);
    float gmx = __uint_as_float(((const unsigned*)(ws + OFF_MINMAX))[1]);
    float* o = out + (size_t)r*34;
#pragma unroll
    for (int q = 0; q < 8; q++) {
        o[q*4+0] = rgb[q].x*2.f - 1.f;
        o[q*4+1] = rgb[q].y*2.f - 1.f;
        o[q*4+2] = rgb[q].z*2.f - 1.f;
        o[q*4+3] = rgb[q].w*2.f - 1.f;
    }
    float depth = dsum/wsum;
    if (depth != depth) depth = __builtin_inff();   // NaN -> inf -> clips to gmax
    depth = fminf(fmaxf(depth, gmn), gmx);
    o[32] = depth;
    o[33] = wsum;
}

extern "C" void kernel_launch(void* const* d_in, const int* in_sizes, int n_in,
                              void* d_out, int out_size, void* d_ws, size_t ws_size,
                              hipStream_t stream) {
    const float* planes = (const float*)d_in[0];
    const float* ro     = (const float*)d_in[1];
    const float* rd     = (const float*)d_in[2];
    const float* noise  = (const float*)d_in[3];
    const float* u      = (const float*)d_in[4];
    const float* W1     = (const float*)d_in[5];
    const float* b1     = (const float*)d_in[6];
    const float* W2     = (const float*)d_in[7];
    const float* b2     = (const float*)d_in[8];
    float* ws  = (float*)d_ws;
    float* out = (float*)d_out;

    hipLaunchKernelGGL(k_init,   dim3(1),          dim3(64),  0, stream, ws, W2);
    hipLaunchKernelGGL(k_depths, dim3(NPTS/256),   dim3(256), 0, stream, noise, ws);
    hipLaunchKernelGGL(k_pass,   dim3(NPTS/256),   dim3(256), 0, stream,
                       planes, ro, rd, ws + OFF_DC, W1, b1, ws + OFF_W2T, b2,
                       ws + OFF_POSES, ws + OFF_CC, ws + OFF_SC);
    hipLaunchKernelGGL(k_imp,    dim3(NRAYS/128),  dim3(128), 0, stream, u, ws);
    hipLaunchKernelGGL(k_pass,   dim3(NPTS/256),   dim3(256), 0, stream,
                       planes, ro, rd, ws + OFF_DF, W1, b1, ws + OFF_W2T, b2,
                       ws + OFF_POSES, ws + OFF_CF, ws + OFF_SF);
    hipLaunchKernelGGL(k_final,  dim3(NRAYS/64),   dim3(64),  0, stream, out, ws);
}

// Round 2
// 757.212 us; speedup vs baseline: 1.6971x; 1.6971x over previous
//
#include <hip/hip_runtime.h>
#include <math.h>

#define B_   2
#define N_   4096
#define S_   48
#define NPL  32
#define NRAYS (B_*N_)          // 8192
#define NPTS  (NRAYS*S_)       // 393216
#define DELTA_ (2.0f/47.0f)

// ---- workspace layout (float offsets) ----
#define OFF_POSES  0                    // 32*12 = 384
#define OFF_MINMAX 384                  // 2 uints (gmin/gmax bit patterns)
#define OFF_W2T    512                  // 33*64 = 2112 (W2 transposed)
#define OFF_DC     4096                 // depths_c [NPTS]; later reused as eC
#define OFF_DF     (OFF_DC+NPTS)        // depths_f [NPTS]; later reused as eF
#define OFF_SC     (OFF_DF+NPTS)        // dens_c   [NPTS]
#define OFF_SF     (OFF_SC+NPTS)        // dens_f   [NPTS]
#define OFF_CC     (OFF_SF+NPTS)        // colors_c [NPTS*32]
#define OFF_CF     (OFF_CC+NPTS*32)     // colors_f [NPTS*32]
// total ~107 MB

__device__ __forceinline__ float softplus_f(float x) {
    return fmaxf(x, 0.f) + log1pf(expf(-fabsf(x)));
}

__device__ void mul3(const double* a, const double* b, double* o) {
    for (int i = 0; i < 3; i++)
        for (int j = 0; j < 3; j++) {
            double s = 0.0;
            for (int k = 0; k < 3; k++) s += a[i*3+k]*b[k*3+j];
            o[i*3+j] = s;
        }
}

// ---- kernel 0: poses (double math), min/max init, W2 transpose ----
__global__ void k_init(float* ws, const float* __restrict__ W2) {
    int t = threadIdx.x;
    if (t < 32) {
        double y = 1.0 - (t/31.0)*2.0;
        double rr = sqrt(fmax(1.0 - y*y, 0.0));
        double golden = M_PI*(sqrt(5.0) - 1.0);
        double th = golden*(double)t;
        double x = cos(th)*rr, z = sin(th)*rr;
        double phi   = atan2(z, sqrt(x*x + y*y));   // radians treated as degrees (faithful)
        double theta = atan2(y, x);
        double p  = phi/180.0*M_PI;
        double tt = theta/180.0*M_PI;
        double e  = 90.0/180.0*M_PI;
        double cp = cos(p), sp = sin(p), ct = cos(tt), st = sin(tt);
        double ce = cos(e), se = sin(e);
        double Ph[9] = {1,0,0,  0,cp,-sp,  0,sp,cp};
        double Th[9] = {ct,0,-st,  0,1,0,  st,0,ct};
        double Et[9] = {ce,se,0,  -se,ce,0,  0,0,1};
        double M3[9] = {-1,0,0,  0,0,1,  0,1,0};
        double A[9], Bm[9], R[9];
        mul3(Th, Ph, A);
        mul3(Et, A, Bm);
        mul3(M3, Bm, R);
        double radius = -1.307;
        double tv0 = radius*R[2], tv1 = radius*R[5], tv2 = radius*R[8];
        double Rf[9] = {-R[0],R[1],R[2], -R[3],R[4],R[5], -R[6],R[7],R[8]};
        float* P = ws + OFF_POSES + t*12;
        for (int j = 0; j < 3; j++) {
            double r0 = Rf[0*3+j], r1 = Rf[1*3+j], r2 = Rf[2*3+j];
            P[j*4+0] = (float)r0;
            P[j*4+1] = (float)r1;
            P[j*4+2] = (float)r2;
            P[j*4+3] = (float)(-(r0*tv0 + r1*tv1 + r2*tv2));
        }
    }
    if (t == 32) ((unsigned*)(ws + OFF_MINMAX))[0] = 0x7F800000u;
    if (t == 33) ((unsigned*)(ws + OFF_MINMAX))[1] = 0u;
    for (int idx = t; idx < 33*64; idx += 64) {
        int jo = idx >> 6, i = idx & 63;
        ws[OFF_W2T + idx] = W2[i*33 + jo];
    }
}

// ---- kernel 1: coarse depths + global min/max ----
__global__ void k_depths(const float* __restrict__ noise, float* ws) {
    int g = blockIdx.x*256 + threadIdx.x;
    if (g >= NPTS) return;
    int j = g % S_;
    float v = 0.5f + (float)j*DELTA_ + noise[g]*DELTA_;
    ws[OFF_DC + g] = v;
    float mn = v, mx = v;
    for (int off = 32; off > 0; off >>= 1) {
        mn = fminf(mn, __shfl_down(mn, off));
        mx = fmaxf(mx, __shfl_down(mx, off));
    }
    if ((threadIdx.x & 63) == 0) {
        atomicMin(((unsigned*)(ws + OFF_MINMAX)) + 0, __float_as_uint(mn));
        atomicMax(((unsigned*)(ws + OFF_MINMAX)) + 1, __float_as_uint(mx));
    }
}

// ---- plane tap helpers (branchless, prefetchable) ----
__device__ __forceinline__ void plane_prep(
    const float* __restrict__ poses, const float* __restrict__ pb, int k,
    float px, float py, float pz,
    float& gx, float& gy, float& wx, float& wy, int& x0, int& y0, float* t)
{
    const float* P = poses + k*12;
    float c0 = fmaf(P[0],px, fmaf(P[1],py, fmaf(P[2],pz, P[3])));
    float c1 = fmaf(P[4],px, fmaf(P[5],py, fmaf(P[6],pz, P[7])));
    float c2 = fmaf(P[8],px, fmaf(P[9],py, fmaf(P[10],pz, P[11])));
    float rz = __builtin_amdgcn_rcpf(c2);
    gx = fminf(fmaxf((1.0254f*c0 + 0.5f*c2)*rz, 0.f), 1.f)*2.f - 1.f;
    gy = fminf(fmaxf((1.0254f*c1 + 0.5f*c2)*rz, 0.f), 1.f)*2.f - 1.f;
    float ix = ((gx + 1.f)*64.f - 1.f)*0.5f;
    float iy = ((gy + 1.f)*64.f - 1.f)*0.5f;
    float x0f = floorf(ix), y0f = floorf(iy);
    wx = ix - x0f; wy = iy - y0f;
    x0 = (int)x0f; y0 = (int)y0f;
    int xc = min(max(x0,0),62);
    int yA = min(max(y0,0),62);
    const float* q = pb + (size_t)(k*3)*4096 + yA*64 + xc;
    t[0]=q[0];    t[1]=q[1];    t[2]=q[64];   t[3]=q[65];
    t[4]=q[4096]; t[5]=q[4097]; t[6]=q[4160]; t[7]=q[4161];
    t[8]=q[8192]; t[9]=q[8193]; t[10]=q[8256];t[11]=q[8257];
}

__device__ __forceinline__ void plane_combine(const float* t, int x0,int y0,float wx,float wy,
                                              float& f0,float& f1,float& f2)
{
    float w0x = (x0>=0)  ? (1.f-wx) : 0.f;
    float w1x = (x0<=62) ? wx       : 0.f;
    float wy0 = (y0>=0)  ? (1.f-wy) : 0.f;
    float wy1 = (y0<=62) ? wy       : 0.f;
    bool xs = (x0==63), ys = (y0==63), xl = (x0==-1), yl = (y0==-1);
    {
        float hA = w0x*(xs?t[1]:t[0]) + w1x*(xl?t[0]:t[1]);
        float hB = w0x*(xs?t[3]:t[2]) + w1x*(xl?t[2]:t[3]);
        f0 = wy0*(ys?hB:hA) + wy1*(yl?hA:hB);
    }
    {
        float hA = w0x*(xs?t[5]:t[4]) + w1x*(xl?t[4]:t[5]);
        float hB = w0x*(xs?t[7]:t[6]) + w1x*(xl?t[6]:t[7]);
        f1 = wy0*(ys?hB:hA) + wy1*(yl?hA:hB);
    }
    {
        float hA = w0x*(xs?t[9]:t[8])   + w1x*(xl?t[8]:t[9]);
        float hB = w0x*(xs?t[11]:t[10]) + w1x*(xl?t[10]:t[11]);
        f2 = wy0*(ys?hB:hA) + wy1*(yl?hA:hB);
    }
}

// ---- kernel 2/4: fused point pass, software-pipelined over planes ----
__global__ __launch_bounds__(256) void k_pass(
    const float* __restrict__ planes, const float* __restrict__ ro,
    const float* __restrict__ rd, const float* __restrict__ depths,
    const float* __restrict__ W1, const float* __restrict__ b1,
    const float* __restrict__ W2t, const float* __restrict__ b2,
    const float* __restrict__ poses,
    float* __restrict__ colors, float* __restrict__ dens)
{
    int g = blockIdx.x*256 + threadIdx.x;
    int ray = g / S_;
    int b = ray >> 12;
    float depth = depths[g];
    float px = fmaf(depth, rd[ray*3+0], ro[ray*3+0]);
    float py = fmaf(depth, rd[ray*3+1], ro[ray*3+1]);
    float pz = fmaf(depth, rd[ray*3+2], ro[ray*3+2]);

    float h[64];
#pragma unroll
    for (int j = 0; j < 64; j++) h[j] = b1[j];

    const float* pb = planes + (size_t)b*96*64*64;

    float tc[12]; float gx,gy,wx,wy; int x0,y0;
    plane_prep(poses, pb, 0, px,py,pz, gx,gy,wx,wy,x0,y0, tc);
    for (int k = 0; k < NPL; k++) {
        float tn[12]; float ngx,ngy,nwx,nwy; int nx0,ny0;
        plane_prep(poses, pb, (k+1<NPL)?(k+1):k, px,py,pz,
                   ngx,ngy,nwx,nwy,nx0,ny0, tn);   // prefetch next plane's taps
        float f0,f1,f2;
        plane_combine(tc, x0,y0,wx,wy, f0,f1,f2);
        const float* w1f = W1 + (k*3)*64;
        const float* w1p = W1 + (96 + 2*k)*64;
#pragma unroll
        for (int j = 0; j < 64; j++) {
            float acc = h[j];
            acc = fmaf(f0, w1f[j],      acc);
            acc = fmaf(f1, w1f[64+j],   acc);
            acc = fmaf(f2, w1f[128+j],  acc);
            acc = fmaf(gx, w1p[j],      acc);
            acc = fmaf(gy, w1p[64+j],   acc);
            h[j] = acc;
        }
#pragma unroll
        for (int i = 0; i < 12; i++) tc[i] = tn[i];
        gx=ngx; gy=ngy; wx=nwx; wy=nwy; x0=nx0; y0=ny0;
    }
#pragma unroll
    for (int j = 0; j < 64; j++) h[j] = softplus_f(h[j]);

    {
        float o0 = b2[0];
#pragma unroll
        for (int i = 0; i < 64; i++) o0 = fmaf(h[i], W2t[i], o0);
        dens[g] = o0;
    }
    float4* cw4 = (float4*)(colors + (size_t)g*32);
#pragma unroll
    for (int q8 = 0; q8 < 8; q8++) {
        float vv[4];
#pragma unroll
        for (int c4 = 0; c4 < 4; c4++) {
            int jo = 1 + q8*4 + c4;
            float acc = b2[jo];
            const float* wr = W2t + jo*64;
#pragma unroll
            for (int i = 0; i < 64; i++) acc = fmaf(h[i], wr[i], acc);
            float sg = 1.f/(1.f + expf(-acc));
            vv[c4] = fmaf(sg, 1.002f, -0.001f);
        }
        cw4[q8] = make_float4(vv[0], vv[1], vv[2], vv[3]);
    }
}

// ---- kernel 3: coarse march + pdf + importance samples (wave per ray) ----
__global__ __launch_bounds__(256) void k_imp(const float* __restrict__ u, float* ws) {
    __shared__ float zl[4][48];
    __shared__ float cdfl[4][46];
    int tid = threadIdx.x;
    int wv = tid >> 6, lane = tid & 63;
    int r = blockIdx.x*4 + wv;
    const float* z   = ws + OFF_DC + (size_t)r*48;
    const float* den = ws + OFF_SC + (size_t)r*48;
    float zv = 0.f, dv = 0.f;
    if (lane < 48) { zv = z[lane]; dv = den[lane]; zl[wv][lane] = zv; }
    float zn  = __shfl_down(zv, 1);
    float dnn = __shfl_down(dv, 1);
    float alpha = 0.f, f = 1.f;
    if (lane < 47) {
        float sp = softplus_f(0.5f*(dv + dnn) - 1.f);
        alpha = 1.f - expf(-sp*(zn - zv));
        f = 1.f - alpha + 1e-10f;
    }
    float v = f;
    for (int off = 1; off < 64; off <<= 1) { float o = __shfl_up(v, off); if (lane >= off) v *= o; }
    float T = __shfl_up(v, 1); if (lane == 0) T = 1.f;
    float w = alpha*T;
    float wn1 = __shfl_down(w, 1), wn2 = __shfl_down(w, 2);
    float pw = 0.f;
    if (lane < 45) pw = 0.5f*(fmaxf(w, wn1) + fmaxf(wn1, wn2)) + 0.01f + 1e-5f;
    float s = pw;
    for (int off = 1; off < 64; off <<= 1) { float o = __shfl_up(s, off); if (lane >= off) s += o; }
    float csum = __shfl(s, 63);
    if (lane < 45) cdfl[wv][lane+1] = s/csum;
    if (lane == 63) cdfl[wv][0] = 0.f;
    __syncthreads();
    if (lane < 48) {
        float uu = u[(size_t)r*48 + lane];
        int lo = 0, hi = 46;
        while (lo < hi) { int mid = (lo+hi)>>1; if (uu >= cdfl[wv][mid]) lo = mid+1; else hi = mid; }
        int below = max(lo-1, 0), above = min(lo, 45);
        float cb = cdfl[wv][below], ca = cdfl[wv][above];
        float zb = zl[wv][below],   za = zl[wv][above];
        float dn2 = ca - cb; if (dn2 < 1e-5f) dn2 = 1.f;
        ws[OFF_DF + (size_t)r*48 + lane] = zb + (uu - cb)/dn2*(za - zb);
    }
}

// ---- kernel 5: merge/sort/march -> per-sample coefficients (wave per ray) ----
__global__ __launch_bounds__(256) void k_march(float* __restrict__ out, float* ws) {
    __shared__ float kd[4][96];
    __shared__ float kden[4][96];
    __shared__ float sdl[4][96];
    __shared__ float sdenl[4][96];
    __shared__ int   sidxl[4][96];
    __shared__ float warr[4][96];
    int tid = threadIdx.x;
    int wv = tid >> 6, lane = tid & 63;
    int r = blockIdx.x*4 + wv;
    const float* dc = ws + OFF_DC + (size_t)r*48;
    const float* df = ws + OFF_DF + (size_t)r*48;
    const float* sc = ws + OFF_SC + (size_t)r*48;
    const float* sf = ws + OFF_SF + (size_t)r*48;
    for (int i = lane; i < 96; i += 64) {
        float d, dn;
        if (i < 48) { d = dc[i]; dn = sc[i]; }
        else        { d = df[i-48]; dn = sf[i-48]; }
        kd[wv][i] = d; kden[wv][i] = dn;
    }
    __syncthreads();
    // stable rank sort: key = (depth, original index)
    for (int i = lane; i < 96; i += 64) {
        float d = kd[wv][i];
        int rank = 0;
        for (int j = 0; j < 96; j++) {
            float dj = kd[wv][j];
            rank += (int)((dj < d) | ((dj == d) & (j < i)));
        }
        sdl[wv][rank] = d; sdenl[wv][rank] = kden[wv][i]; sidxl[wv][rank] = i;
    }
    __syncthreads();
    int i2 = 2*lane;
    float a0=0.f, f0=1.f, a1=0.f, f1=1.f, d0=0.f, d1=0.f, d2=0.f;
    if (i2 < 95) {
        d0 = sdl[wv][i2]; d1 = sdl[wv][i2+1];
        float sp = softplus_f(0.5f*(sdenl[wv][i2] + sdenl[wv][i2+1]) - 1.f);
        a0 = 1.f - expf(-sp*(d1 - d0)); f0 = 1.f - a0 + 1e-10f;
    }
    if (i2+1 < 95) {
        d2 = sdl[wv][i2+2];
        float sp = softplus_f(0.5f*(sdenl[wv][i2+1] + sdenl[wv][i2+2]) - 1.f);
        a1 = 1.f - expf(-sp*(d2 - d1)); f1 = 1.f - a1 + 1e-10f;
    }
    float p = f0*f1, v = p;
    for (int off = 1; off < 64; off <<= 1) { float o = __shfl_up(v, off); if (lane >= off) v *= o; }
    float excl = __shfl_up(v, 1); if (lane == 0) excl = 1.f;
    float w0 = a0*excl, w1 = a1*excl*f0;
    if (i2   < 96) warr[wv][i2]   = w0;
    if (i2+1 < 96) warr[wv][i2+1] = w1;
    float wsm = w0 + w1;
    float dsm = w0*0.5f*(d0+d1) + w1*0.5f*(d1+d2);
    for (int off = 32; off; off >>= 1) { wsm += __shfl_xor(wsm, off); dsm += __shfl_xor(dsm, off); }
    __syncthreads();
    // e_j = 0.5*(w_{j-1}+w_j) scattered back by original index (in place over DC/DF)
    for (int i = lane; i < 96; i += 64) {
        float wp = (i > 0)  ? warr[wv][i-1] : 0.f;
        float wc = (i < 95) ? warr[wv][i]   : 0.f;
        float e = 0.5f*(wp + wc);
        int orig = sidxl[wv][i];
        if (orig < 48) ws[OFF_DC + (size_t)r*48 + orig]      = e;
        else           ws[OFF_DF + (size_t)r*48 + orig - 48] = e;
    }
    if (lane == 0) {
        float gmn = __uint_as_float(((const unsigned*)(ws + OFF_MINMAX))[0]);
        float gmx = __uint_as_float(((const unsigned*)(ws + OFF_MINMAX))[1]);
        float depth = dsm/wsm;
        if (depth != depth) depth = __builtin_inff();
        depth = fminf(fmaxf(depth, gmn), gmx);
        out[(size_t)r*34 + 32] = depth;
        out[(size_t)r*34 + 33] = wsm;
    }
}

// ---- kernel 6: coalesced color accumulation (8 threads per ray) ----
__global__ __launch_bounds__(256) void k_accum(float* __restrict__ out, const float* __restrict__ ws) {
    int t = blockIdx.x*256 + threadIdx.x;
    int r = t >> 3, q = t & 7;
    const float* eC = ws + OFF_DC + (size_t)r*48;
    const float* eF = ws + OFF_DF + (size_t)r*48;
    const float4* cC4 = (const float4*)(ws + OFF_CC) + (size_t)r*48*8 + q;
    const float4* cF4 = (const float4*)(ws + OFF_CF) + (size_t)r*48*8 + q;
    float ax=0.f, ay=0.f, az=0.f, aw=0.f;
    for (int j = 0; j < 48; j++) {
        float e = eC[j]; float4 c = cC4[(size_t)j*8];
        ax = fmaf(e, c.x, ax); ay = fmaf(e, c.y, ay);
        az = fmaf(e, c.z, az); aw = fmaf(e, c.w, aw);
    }
    for (int j = 0; j < 48; j++) {
        float e = eF[j]; float4 c = cF4[(size_t)j*8];
        ax = fmaf(e, c.x, ax); ay = fmaf(e, c.y, ay);
        az = fmaf(e, c.z, az); aw = fmaf(e, c.w, aw);
    }
    float* o = out + (size_t)r*34 + q*4;
    o[0] = 2.f*ax - 1.f; o[1] = 2.f*ay - 1.f;
    o[2] = 2.f*az - 1.f; o[3] = 2.f*aw - 1.f;
}

extern "C" void kernel_launch(void* const* d_in, const int* in_sizes, int n_in,
                              void* d_out, int out_size, void* d_ws, size_t ws_size,
                              hipStream_t stream) {
    const float* planes = (const float*)d_in[0];
    const float* ro     = (const float*)d_in[1];
    const float* rd     = (const float*)d_in[2];
    const float* noise  = (const float*)d_in[3];
    const float* u      = (const float*)d_in[4];
    const float* W1     = (const float*)d_in[5];
    const float* b1     = (const float*)d_in[6];
    const float* W2     = (const float*)d_in[7];
    const float* b2     = (const float*)d_in[8];
    float* ws  = (float*)d_ws;
    float* out = (float*)d_out;

    hipLaunchKernelGGL(k_init,   dim3(1),           dim3(64),  0, stream, ws, W2);
    hipLaunchKernelGGL(k_depths, dim3(NPTS/256),    dim3(256), 0, stream, noise, ws);
    hipLaunchKernelGGL(k_pass,   dim3(NPTS/256),    dim3(256), 0, stream,
                       planes, ro, rd, ws + OFF_DC, W1, b1, ws + OFF_W2T, b2,
                       ws + OFF_POSES, ws + OFF_CC, ws + OFF_SC);
    hipLaunchKernelGGL(k_imp,    dim3(NRAYS/4),     dim3(256), 0, stream, u, ws);
    hipLaunchKernelGGL(k_pass,   dim3(NPTS/256),    dim3(256), 0, stream,
                       planes, ro, rd, ws + OFF_DF, W1, b1, ws + OFF_W2T, b2,
                       ws + OFF_POSES, ws + OFF_CF, ws + OFF_SF);
    hipLaunchKernelGGL(k_march,  dim3(NRAYS/4),     dim3(256), 0, stream, out, ws);
    hipLaunchKernelGGL(k_accum,  dim3(NRAYS*8/256), dim3(256), 0, stream, out, ws);
}

// Round 3
// 616.831 us; speedup vs baseline: 2.0834x; 1.2276x over previous
//
#include <hip/hip_runtime.h>
#include <math.h>

#define B_   2
#define N_   4096
#define S_   48
#define NPL  32
#define NRAYS (B_*N_)          // 8192
#define NPTS  (NRAYS*S_)       // 393216
#define DELTA_ (2.0f/47.0f)

// ---- workspace layout (float offsets) ----
#define OFF_POSES  0                    // 32*12 = 384
#define OFF_MINMAX 384                  // 2 uints
#define OFF_W1E    512                  // 64*256 bf16 = 8192 floats (W1^T expanded, K=256)
#define OFF_W2E    8704                 // 48*64 bf16 = 1536 floats (W2^T padded N=48)
#define OFF_B2E    10240                // 48 floats
#define OFF_DC     16384                // depths_c [NPTS]; reused as eC
#define OFF_DF     (OFF_DC+NPTS)        // depths_f [NPTS]; reused as eF
#define OFF_SC     (OFF_DF+NPTS)        // dens_c   [NPTS]
#define OFF_SF     (OFF_SC+NPTS)        // dens_f   [NPTS]
#define OFF_CC     (OFF_SF+NPTS)        // colors_c [NPTS*32]
#define OFF_CF     (OFF_CC+NPTS*32)     // colors_f [NPTS*32]

typedef __attribute__((ext_vector_type(8))) short short8;
typedef __attribute__((ext_vector_type(4))) float f32x4;

__device__ __forceinline__ float softplus_f(float x) {
    return fmaxf(x, 0.f) + log1pf(expf(-fabsf(x)));
}
__device__ __forceinline__ unsigned short bf16rne(float x) {
    unsigned u = __float_as_uint(x);
    u += 0x7FFFu + ((u >> 16) & 1u);
    return (unsigned short)(u >> 16);
}

__device__ void mul3(const double* a, const double* b, double* o) {
    for (int i = 0; i < 3; i++)
        for (int j = 0; j < 3; j++) {
            double s = 0.0;
            for (int k = 0; k < 3; k++) s += a[i*3+k]*b[k*3+j];
            o[i*3+j] = s;
        }
}

// ---- kernel 0: poses (double math), min/max init, expanded bf16 weights ----
__global__ void k_init(float* ws, const float* __restrict__ W1,
                       const float* __restrict__ W2, const float* __restrict__ b2) {
    int t = threadIdx.x;
    if (t < 32) {
        double y = 1.0 - (t/31.0)*2.0;
        double rr = sqrt(fmax(1.0 - y*y, 0.0));
        double golden = M_PI*(sqrt(5.0) - 1.0);
        double th = golden*(double)t;
        double x = cos(th)*rr, z = sin(th)*rr;
        double phi   = atan2(z, sqrt(x*x + y*y));   // radians treated as degrees (faithful)
        double theta = atan2(y, x);
        double p  = phi/180.0*M_PI;
        double tt = theta/180.0*M_PI;
        double e  = 90.0/180.0*M_PI;
        double cp = cos(p), sp = sin(p), ct = cos(tt), st = sin(tt);
        double ce = cos(e), se = sin(e);
        double Ph[9] = {1,0,0,  0,cp,-sp,  0,sp,cp};
        double Th[9] = {ct,0,-st,  0,1,0,  st,0,ct};
        double Et[9] = {ce,se,0,  -se,ce,0,  0,0,1};
        double M3[9] = {-1,0,0,  0,0,1,  0,1,0};
        double A[9], Bm[9], R[9];
        mul3(Th, Ph, A);
        mul3(Et, A, Bm);
        mul3(M3, Bm, R);
        double radius = -1.307;
        double tv0 = radius*R[2], tv1 = radius*R[5], tv2 = radius*R[8];
        double Rf[9] = {-R[0],R[1],R[2], -R[3],R[4],R[5], -R[6],R[7],R[8]};
        float* P = ws + OFF_POSES + t*12;
        for (int j = 0; j < 3; j++) {
            double r0 = Rf[0*3+j], r1 = Rf[1*3+j], r2 = Rf[2*3+j];
            P[j*4+0] = (float)r0;
            P[j*4+1] = (float)r1;
            P[j*4+2] = (float)r2;
            P[j*4+3] = (float)(-(r0*tv0 + r1*tv1 + r2*tv2));
        }
    }
    if (t == 32) ((unsigned*)(ws + OFF_MINMAX))[0] = 0x7F800000u;
    if (t == 33) ((unsigned*)(ws + OFF_MINMAX))[1] = 0u;
    // W1t_e[64n][256k] bf16: k = 8*plane + f, f in {c0,c1,c2,gx,gy,0,0,0}
    unsigned short* w1e = (unsigned short*)(ws + OFF_W1E);
    for (int idx = t; idx < 64*256; idx += 256) {
        int n = idx >> 8, k = idx & 255;
        int p = k >> 3, f = k & 7;
        float v = 0.f;
        if (f < 3)      v = W1[(3*p+f)*64 + n];
        else if (f < 5) v = W1[(96 + 2*p + (f-3))*64 + n];
        w1e[idx] = bf16rne(v);
    }
    // W2t_e[48n][64k] bf16
    unsigned short* w2e = (unsigned short*)(ws + OFF_W2E);
    for (int idx = t; idx < 48*64; idx += 256) {
        int n = idx >> 6, k = idx & 63;
        float v = (n < 33) ? W2[k*33 + n] : 0.f;
        w2e[idx] = bf16rne(v);
    }
    for (int idx = t; idx < 48; idx += 256)
        ws[OFF_B2E + idx] = (idx < 33) ? b2[idx] : 0.f;
}

// ---- kernel 1: coarse depths + global min/max ----
__global__ void k_depths(const float* __restrict__ noise, float* ws) {
    int g = blockIdx.x*256 + threadIdx.x;
    if (g >= NPTS) return;
    int j = g % S_;
    float v = 0.5f + (float)j*DELTA_ + noise[g]*DELTA_;
    ws[OFF_DC + g] = v;
    float mn = v, mx = v;
    for (int off = 32; off > 0; off >>= 1) {
        mn = fminf(mn, __shfl_down(mn, off));
        mx = fmaxf(mx, __shfl_down(mx, off));
    }
    if ((threadIdx.x & 63) == 0) {
        atomicMin(((unsigned*)(ws + OFF_MINMAX)) + 0, __float_as_uint(mn));
        atomicMax(((unsigned*)(ws + OFF_MINMAX)) + 1, __float_as_uint(mx));
    }
}

// sample one plane at one point: 12 tap loads + branchless bilinear
__device__ __forceinline__ void sample_plane(
    const float* __restrict__ P, const float* __restrict__ cb0,
    float px, float py, float pz,
    float& f0, float& f1, float& f2, float& gx, float& gy)
{
    float c0 = fmaf(P[0],px, fmaf(P[1],py, fmaf(P[2],pz, P[3])));
    float c1 = fmaf(P[4],px, fmaf(P[5],py, fmaf(P[6],pz, P[7])));
    float c2 = fmaf(P[8],px, fmaf(P[9],py, fmaf(P[10],pz, P[11])));
    float rz = __builtin_amdgcn_rcpf(c2);
    gx = fminf(fmaxf((1.0254f*c0 + 0.5f*c2)*rz, 0.f), 1.f)*2.f - 1.f;
    gy = fminf(fmaxf((1.0254f*c1 + 0.5f*c2)*rz, 0.f), 1.f)*2.f - 1.f;
    float ix = ((gx + 1.f)*64.f - 1.f)*0.5f;
    float iy = ((gy + 1.f)*64.f - 1.f)*0.5f;
    float x0f = floorf(ix), y0f = floorf(iy);
    float wx = ix - x0f, wy = iy - y0f;
    int x0 = (int)x0f, y0 = (int)y0f;
    int xc = min(max(x0,0),62), yA = min(max(y0,0),62);
    const float* q = cb0 + yA*64 + xc;
    float t0=q[0],    t1=q[1],    t2=q[64],   t3=q[65];
    float t4=q[4096], t5=q[4097], t6=q[4160], t7=q[4161];
    float t8=q[8192], t9=q[8193], t10=q[8256],t11=q[8257];
    float w0x = (x0>=0)  ? (1.f-wx) : 0.f;
    float w1x = (x0<=62) ? wx       : 0.f;
    float wy0 = (y0>=0)  ? (1.f-wy) : 0.f;
    float wy1 = (y0<=62) ? wy       : 0.f;
    bool xs = (x0==63), ys = (y0==63), xl = (x0==-1), yl = (y0==-1);
    {
        float hA = w0x*(xs?t1:t0) + w1x*(xl?t0:t1);
        float hB = w0x*(xs?t3:t2) + w1x*(xl?t2:t3);
        f0 = wy0*(ys?hB:hA) + wy1*(yl?hA:hB);
    }
    {
        float hA = w0x*(xs?t5:t4) + w1x*(xl?t4:t5);
        float hB = w0x*(xs?t7:t6) + w1x*(xl?t6:t7);
        f1 = wy0*(ys?hB:hA) + wy1*(yl?hA:hB);
    }
    {
        float hA = w0x*(xs?t9:t8)   + w1x*(xl?t8:t9);
        float hB = w0x*(xs?t11:t10) + w1x*(xl?t10:t11);
        f2 = wy0*(ys?hB:hA) + wy1*(yl?hA:hB);
    }
}

// ---- kernel 2/4: fused point pass, MFMA MLP (wave = 64 points) ----
__global__ __launch_bounds__(256) void k_pass(
    const float* __restrict__ planes, const float* __restrict__ ro,
    const float* __restrict__ rd, const float* __restrict__ depths,
    const float* __restrict__ b1, const unsigned short* __restrict__ w1e,
    const unsigned short* __restrict__ w2e, const float* __restrict__ b2e,
    const float* __restrict__ poses,
    float* __restrict__ colors, float* __restrict__ dens)
{
    __shared__ __align__(16) unsigned short smem[4][4608];  // 9216B/wave: h-tile then out-tile
    __shared__ float pls[384];
    int tid = threadIdx.x;
    int wv = tid >> 6, lane = tid & 63;
    int n = lane & 15, q = lane >> 4;
    int wbase = blockIdx.x*256 + wv*64;
    int b = (wbase >= NPTS/2) ? 1 : 0;
    for (int i = tid; i < 384; i += 256) pls[i] = poses[i];
    __syncthreads();

    // positions of this lane's 4 m-tile points
    float px[4], py[4], pz[4];
#pragma unroll
    for (int t = 0; t < 4; t++) {
        int pt = wbase + t*16 + n;
        int ray = pt / S_;
        float depth = depths[pt];
        px[t] = fmaf(depth, rd[ray*3+0], ro[ray*3+0]);
        py[t] = fmaf(depth, rd[ray*3+1], ro[ray*3+1]);
        pz[t] = fmaf(depth, rd[ray*3+2], ro[ray*3+2]);
    }

    f32x4 acc[4][4];
#pragma unroll
    for (int t = 0; t < 4; t++)
#pragma unroll
        for (int nt = 0; nt < 4; nt++) {
            float bv = b1[nt*16 + n];
            acc[t][nt] = (f32x4){bv, bv, bv, bv};
        }

    const float* pb = planes + (size_t)b*96*4096;

    for (int s = 0; s < 8; s++) {
        int plane = s*4 + q;                       // this lane-quad's plane
        // B-fragments (L1-hot 16B loads)
        short8 bf[4];
#pragma unroll
        for (int nt = 0; nt < 4; nt++)
            bf[nt] = *(const short8*)(w1e + (nt*16 + n)*256 + s*32 + q*8);
        // A-fragments: sample this plane at 4 points, pack bf16
        short8 af[4];
        const float* P = pls + plane*12;
        const float* cb0 = pb + (size_t)plane*3*4096;
#pragma unroll
        for (int t = 0; t < 4; t++) {
            float f0, f1, f2, gx, gy;
            sample_plane(P, cb0, px[t], py[t], pz[t], f0, f1, f2, gx, gy);
            short8 a = {0,0,0,0,0,0,0,0};
            a[0] = (short)bf16rne(f0);
            a[1] = (short)bf16rne(f1);
            a[2] = (short)bf16rne(f2);
            a[3] = (short)bf16rne(gx);
            a[4] = (short)bf16rne(gy);
            af[t] = a;
        }
#pragma unroll
        for (int t = 0; t < 4; t++)
#pragma unroll
            for (int nt = 0; nt < 4; nt++)
                acc[t][nt] = __builtin_amdgcn_mfma_f32_16x16x32_bf16(af[t], bf[nt], acc[t][nt], 0, 0, 0);
    }

    // softplus + h-tile to LDS (bf16, stride 72: 2-way banks = free)
    unsigned short* ht = &smem[wv][0];
#pragma unroll
    for (int t = 0; t < 4; t++)
#pragma unroll
        for (int nt = 0; nt < 4; nt++)
#pragma unroll
            for (int r = 0; r < 4; r++) {
                float hv = softplus_f(acc[t][nt][r]);
                ht[(t*16 + q*4 + r)*72 + nt*16 + n] = bf16rne(hv);
            }
    // A2-fragments from h-tile
    short8 a2[4][2];
#pragma unroll
    for (int t = 0; t < 4; t++)
#pragma unroll
        for (int s2 = 0; s2 < 2; s2++)
            a2[t][s2] = *(const short8*)(ht + (t*16 + n)*72 + s2*32 + q*8);
    __syncthreads();   // fence before out-tile aliases the h-tile region

    f32x4 acc2[4][3];
#pragma unroll
    for (int t = 0; t < 4; t++)
#pragma unroll
        for (int nt = 0; nt < 3; nt++) {
            float bv = b2e[nt*16 + n];
            acc2[t][nt] = (f32x4){bv, bv, bv, bv};
        }
    short8 b2f[3][2];
#pragma unroll
    for (int nt = 0; nt < 3; nt++)
#pragma unroll
        for (int s2 = 0; s2 < 2; s2++)
            b2f[nt][s2] = *(const short8*)(w2e + (nt*16 + n)*64 + s2*32 + q*8);
#pragma unroll
    for (int t = 0; t < 4; t++)
#pragma unroll
        for (int nt = 0; nt < 3; nt++)
#pragma unroll
            for (int s2 = 0; s2 < 2; s2++)
                acc2[t][nt] = __builtin_amdgcn_mfma_f32_16x16x32_bf16(a2[t][s2], b2f[nt][s2], acc2[t][nt], 0, 0, 0);

    // out-tile [64][34] f32 (cols 0..31 rgb, 32 sigma), stride 34: conflict-free
    float* ot = (float*)&smem[wv][0];
#pragma unroll
    for (int t = 0; t < 4; t++)
#pragma unroll
        for (int nt = 0; nt < 3; nt++) {
            int col = nt*16 + n;
#pragma unroll
            for (int r = 0; r < 4; r++) {
                float v = acc2[t][nt][r];
                int row = t*16 + q*4 + r;
                if (col == 0) ot[row*34 + 32] = v;
                else if (col <= 32) {
                    float sg = 1.f/(1.f + expf(-v));
                    ot[row*34 + (col-1)] = fmaf(sg, 1.002f, -0.001f);
                }
            }
        }
    // coalesced global writes
    float* cg = colors + (size_t)wbase*32;
    for (int i = 0; i < 32; i++) {
        int idx = i*64 + lane;
        cg[idx] = ot[(idx >> 5)*34 + (idx & 31)];
    }
    dens[wbase + lane] = ot[lane*34 + 32];
}

// ---- kernel 3: coarse march + pdf + importance samples (wave per ray) ----
__global__ __launch_bounds__(256) void k_imp(const float* __restrict__ u, float* ws) {
    __shared__ float zl[4][48];
    __shared__ float cdfl[4][46];
    int tid = threadIdx.x;
    int wv = tid >> 6, lane = tid & 63;
    int r = blockIdx.x*4 + wv;
    const float* z   = ws + OFF_DC + (size_t)r*48;
    const float* den = ws + OFF_SC + (size_t)r*48;
    float zv = 0.f, dv = 0.f;
    if (lane < 48) { zv = z[lane]; dv = den[lane]; zl[wv][lane] = zv; }
    float zn  = __shfl_down(zv, 1);
    float dnn = __shfl_down(dv, 1);
    float alpha = 0.f, f = 1.f;
    if (lane < 47) {
        float sp = softplus_f(0.5f*(dv + dnn) - 1.f);
        alpha = 1.f - expf(-sp*(zn - zv));
        f = 1.f - alpha + 1e-10f;
    }
    float v = f;
    for (int off = 1; off < 64; off <<= 1) { float o = __shfl_up(v, off); if (lane >= off) v *= o; }
    float T = __shfl_up(v, 1); if (lane == 0) T = 1.f;
    float w = alpha*T;
    float wn1 = __shfl_down(w, 1), wn2 = __shfl_down(w, 2);
    float pw = 0.f;
    if (lane < 45) pw = 0.5f*(fmaxf(w, wn1) + fmaxf(wn1, wn2)) + 0.01f + 1e-5f;
    float s = pw;
    for (int off = 1; off < 64; off <<= 1) { float o = __shfl_up(s, off); if (lane >= off) s += o; }
    float csum = __shfl(s, 63);
    if (lane < 45) cdfl[wv][lane+1] = s/csum;
    if (lane == 63) cdfl[wv][0] = 0.f;
    __syncthreads();
    if (lane < 48) {
        float uu = u[(size_t)r*48 + lane];
        int lo = 0, hi = 46;
        while (lo < hi) { int mid = (lo+hi)>>1; if (uu >= cdfl[wv][mid]) lo = mid+1; else hi = mid; }
        int below = max(lo-1, 0), above = min(lo, 45);
        float cb = cdfl[wv][below], ca = cdfl[wv][above];
        float zb = zl[wv][below],   za = zl[wv][above];
        float dn2 = ca - cb; if (dn2 < 1e-5f) dn2 = 1.f;
        ws[OFF_DF + (size_t)r*48 + lane] = zb + (uu - cb)/dn2*(za - zb);
    }
}

// ---- kernel 5: merge/sort/march -> per-sample coefficients (wave per ray) ----
__global__ __launch_bounds__(256) void k_march(float* __restrict__ out, float* ws) {
    __shared__ float kd[4][96];
    __shared__ float kden[4][96];
    __shared__ float sdl[4][96];
    __shared__ float sdenl[4][96];
    __shared__ int   sidxl[4][96];
    __shared__ float warr[4][96];
    int tid = threadIdx.x;
    int wv = tid >> 6, lane = tid & 63;
    int r = blockIdx.x*4 + wv;
    const float* dc = ws + OFF_DC + (size_t)r*48;
    const float* df = ws + OFF_DF + (size_t)r*48;
    const float* sc = ws + OFF_SC + (size_t)r*48;
    const float* sf = ws + OFF_SF + (size_t)r*48;
    for (int i = lane; i < 96; i += 64) {
        float d, dn;
        if (i < 48) { d = dc[i]; dn = sc[i]; }
        else        { d = df[i-48]; dn = sf[i-48]; }
        kd[wv][i] = d; kden[wv][i] = dn;
    }
    __syncthreads();
    for (int i = lane; i < 96; i += 64) {
        float d = kd[wv][i];
        int rank = 0;
        for (int j = 0; j < 96; j++) {
            float dj = kd[wv][j];
            rank += (int)((dj < d) | ((dj == d) & (j < i)));
        }
        sdl[wv][rank] = d; sdenl[wv][rank] = kden[wv][i]; sidxl[wv][rank] = i;
    }
    __syncthreads();
    int i2 = 2*lane;
    float a0=0.f, f0=1.f, a1=0.f, f1=1.f, d0=0.f, d1=0.f, d2=0.f;
    if (i2 < 95) {
        d0 = sdl[wv][i2]; d1 = sdl[wv][i2+1];
        float sp = softplus_f(0.5f*(sdenl[wv][i2] + sdenl[wv][i2+1]) - 1.f);
        a0 = 1.f - expf(-sp*(d1 - d0)); f0 = 1.f - a0 + 1e-10f;
    }
    if (i2+1 < 95) {
        d2 = sdl[wv][i2+2];
        float sp = softplus_f(0.5f*(sdenl[wv][i2+1] + sdenl[wv][i2+2]) - 1.f);
        a1 = 1.f - expf(-sp*(d2 - d1)); f1 = 1.f - a1 + 1e-10f;
    }
    float p = f0*f1, v = p;
    for (int off = 1; off < 64; off <<= 1) { float o = __shfl_up(v, off); if (lane >= off) v *= o; }
    float excl = __shfl_up(v, 1); if (lane == 0) excl = 1.f;
    float w0 = a0*excl, w1 = a1*excl*f0;
    if (i2   < 96) warr[wv][i2]   = w0;
    if (i2+1 < 96) warr[wv][i2+1] = w1;
    float wsm = w0 + w1;
    float dsm = w0*0.5f*(d0+d1) + w1*0.5f*(d1+d2);
    for (int off = 32; off; off >>= 1) { wsm += __shfl_xor(wsm, off); dsm += __shfl_xor(dsm, off); }
    __syncthreads();
    for (int i = lane; i < 96; i += 64) {
        float wp = (i > 0)  ? warr[wv][i-1] : 0.f;
        float wc = (i < 95) ? warr[wv][i]   : 0.f;
        float e = 0.5f*(wp + wc);
        int orig = sidxl[wv][i];
        if (orig < 48) ws[OFF_DC + (size_t)r*48 + orig]      = e;
        else           ws[OFF_DF + (size_t)r*48 + orig - 48] = e;
    }
    if (lane == 0) {
        float gmn = __uint_as_float(((const unsigned*)(ws + OFF_MINMAX))[0]);
        float gmx = __uint_as_float(((const unsigned*)(ws + OFF_MINMAX))[1]);
        float depth = dsm/wsm;
        if (depth != depth) depth = __builtin_inff();
        depth = fminf(fmaxf(depth, gmn), gmx);
        out[(size_t)r*34 + 32] = depth;
        out[(size_t)r*34 + 33] = wsm;
    }
}

// ---- kernel 6: coalesced color accumulation (8 threads per ray) ----
__global__ __launch_bounds__(256) void k_accum(float* __restrict__ out, const float* __restrict__ ws) {
    int t = blockIdx.x*256 + threadIdx.x;
    int r = t >> 3, q = t & 7;
    const float* eC = ws + OFF_DC + (size_t)r*48;
    const float* eF = ws + OFF_DF + (size_t)r*48;
    const float4* cC4 = (const float4*)(ws + OFF_CC) + (size_t)r*48*8 + q;
    const float4* cF4 = (const float4*)(ws + OFF_CF) + (size_t)r*48*8 + q;
    float ax=0.f, ay=0.f, az=0.f, aw=0.f;
    for (int j = 0; j < 48; j++) {
        float e = eC[j]; float4 c = cC4[(size_t)j*8];
        ax = fmaf(e, c.x, ax); ay = fmaf(e, c.y, ay);
        az = fmaf(e, c.z, az); aw = fmaf(e, c.w, aw);
    }
    for (int j = 0; j < 48; j++) {
        float e = eF[j]; float4 c = cF4[(size_t)j*8];
        ax = fmaf(e, c.x, ax); ay = fmaf(e, c.y, ay);
        az = fmaf(e, c.z, az); aw = fmaf(e, c.w, aw);
    }
    float* o = out + (size_t)r*34 + q*4;
    o[0] = 2.f*ax - 1.f; o[1] = 2.f*ay - 1.f;
    o[2] = 2.f*az - 1.f; o[3] = 2.f*aw - 1.f;
}

extern "C" void kernel_launch(void* const* d_in, const int* in_sizes, int n_in,
                              void* d_out, int out_size, void* d_ws, size_t ws_size,
                              hipStream_t stream) {
    const float* planes = (const float*)d_in[0];
    const float* ro     = (const float*)d_in[1];
    const float* rd     = (const float*)d_in[2];
    const float* noise  = (const float*)d_in[3];
    const float* u      = (const float*)d_in[4];
    const float* W1     = (const float*)d_in[5];
    const float* b1     = (const float*)d_in[6];
    const float* W2     = (const float*)d_in[7];
    const float* b2     = (const float*)d_in[8];
    float* ws  = (float*)d_ws;
    float* out = (float*)d_out;
    const unsigned short* w1e = (const unsigned short*)(ws + OFF_W1E);
    const unsigned short* w2e = (const unsigned short*)(ws + OFF_W2E);

    hipLaunchKernelGGL(k_init,   dim3(1),           dim3(256), 0, stream, ws, W1, W2, b2);
    hipLaunchKernelGGL(k_depths, dim3(NPTS/256),    dim3(256), 0, stream, noise, ws);
    hipLaunchKernelGGL(k_pass,   dim3(NPTS/256),    dim3(256), 0, stream,
                       planes, ro, rd, ws + OFF_DC, b1, w1e, w2e, ws + OFF_B2E,
                       ws + OFF_POSES, ws + OFF_CC, ws + OFF_SC);
    hipLaunchKernelGGL(k_imp,    dim3(NRAYS/4),     dim3(256), 0, stream, u, ws);
    hipLaunchKernelGGL(k_pass,   dim3(NPTS/256),    dim3(256), 0, stream,
                       planes, ro, rd, ws + OFF_DF, b1, w1e, w2e, ws + OFF_B2E,
                       ws + OFF_POSES, ws + OFF_CF, ws + OFF_SF);
    hipLaunchKernelGGL(k_march,  dim3(NRAYS/4),     dim3(256), 0, stream, out, ws);
    hipLaunchKernelGGL(k_accum,  dim3(NRAYS*8/256), dim3(256), 0, stream, out, ws);
}